// Round 9
// baseline (537.699 us; speedup 1.0000x reference)
//
#include <hip/hip_runtime.h>
#include <cstdint>

#define M_DIM 8192
#define K_DIM 4096
#define N_DIM 12288
#define KT 64  // K-tiles of BK=64 int8 (64 B per row)

using i32x4 = __attribute__((ext_vector_type(4))) int;

__device__ inline void gload_lds16(const void* g, void* l) {
    __builtin_amdgcn_global_load_lds(
        (const __attribute__((address_space(1))) void*)g,
        (__attribute__((address_space(3))) void*)l,
        16, 0, 0);
}

// ---------------- fused: per-row quant (blocks 0..M-1) + weight repack ----------------
__global__ __launch_bounds__(256) void quant_pack(const float* __restrict__ x,
                                                  const int* __restrict__ w32,
                                                  int8_t* __restrict__ qa,
                                                  float* __restrict__ ascale,
                                                  int8_t* __restrict__ wq) {
    const int t = threadIdx.x;
    if (blockIdx.x < M_DIM) {
        const int row = blockIdx.x;
        const float4* xr = (const float4*)(x + (size_t)row * K_DIM);
        float4 v[4];
        float amax = 0.0f;
#pragma unroll
        for (int c = 0; c < 4; ++c) {
            v[c] = xr[t + 256 * c];
            amax = fmaxf(amax, fmaxf(fmaxf(fabsf(v[c].x), fabsf(v[c].y)),
                                     fmaxf(fabsf(v[c].z), fabsf(v[c].w))));
        }
#pragma unroll
        for (int off = 32; off > 0; off >>= 1)
            amax = fmaxf(amax, __shfl_xor(amax, off));
        __shared__ float smax[4];
        if ((t & 63) == 0) smax[t >> 6] = amax;
        __syncthreads();
        amax = fmaxf(fmaxf(smax[0], smax[1]), fmaxf(smax[2], smax[3]));
        const float sc = amax * (1.0f / 127.0f);
        const float inv = (amax > 0.0f) ? (127.0f / amax) : 0.0f;
        if (t == 0) ascale[row] = sc;

        int* q32 = (int*)(qa + (size_t)row * K_DIM);
#pragma unroll
        for (int c = 0; c < 4; ++c) {
            int q0 = (int)rintf(v[c].x * inv);
            int q1 = (int)rintf(v[c].y * inv);
            int q2 = (int)rintf(v[c].z * inv);
            int q3 = (int)rintf(v[c].w * inv);
            q0 = min(127, max(-128, q0));
            q1 = min(127, max(-128, q1));
            q2 = min(127, max(-128, q2));
            q3 = min(127, max(-128, q3));
            q32[t + 256 * c] = (q0 & 255) | ((q1 & 255) << 8) | ((q2 & 255) << 16) | (q3 << 24);
        }
    } else {
        const int pb = blockIdx.x - M_DIM;  // 0..2047
        const size_t total4 = (size_t)N_DIM * K_DIM / 4;
        const size_t stride = (size_t)2048 * 256;
        int* out32 = (int*)wq;
        for (size_t i = (size_t)pb * 256 + t; i < total4; i += stride) {
            const int4 v = ((const int4*)w32)[i];
            out32[i] = (v.x & 255) | ((v.y & 255) << 8) | ((v.z & 255) << 16) | (v.w << 24);
        }
    }
}

// ---- int8 GEMM: 256x256, BK=64, ring-4, read-one-phase-ahead + counted lgkmcnt ----
__global__ __launch_bounds__(512, 2) void gemm_i8(const int8_t* __restrict__ qa,
                                                  const int8_t* __restrict__ wq,
                                                  const float* __restrict__ ascale,
                                                  const float* __restrict__ wscale,
                                                  const float* __restrict__ bias,
                                                  float* __restrict__ out) {
    __shared__ int8_t lds[4][2][16384];  // ring-4 K-tile slots x {A,B}, 128 KiB

    const int t = threadIdx.x;
    const int lane = t & 63;
    const int wave = t >> 6;       // 0..7
    const int wm = wave >> 2;      // 0..1 -> 128 rows of A
    const int wn = wave & 3;       // 0..3 -> 64 rows of B
    const int lrow = lane & 15;
    const int lk = lane >> 4;      // 0..3
    const int rslot = (lk ^ ((lrow >> 1) & 3)) << 4;  // r5 swizzle: measured 0 conflicts

    // XCD-aware bijective swizzle: 1536 = 8 * 192
    const int flat = blockIdx.x;
    const int sw = (flat & 7) * 192 + (flat >> 3);
    const int bm = sw / 48;
    const int bn = sw % 48;

    // r5 staging involution: linear LDS dest (slots t, t+512), global k-slot permuted
    const int g = (t & 3) ^ ((t >> 3) & 3);
    const size_t aoff0 = (size_t)(bm * 256 + (t >> 2)) * K_DIM + (size_t)g * 16;
    const size_t aoff1 = aoff0 + (size_t)128 * K_DIM;
    const size_t boff0 = (size_t)(bn * 256 + (t >> 2)) * K_DIM + (size_t)g * 16;
    const size_t boff1 = boff0 + (size_t)128 * K_DIM;

#define STAGE_A(sb, jt)                                                        \
    {                                                                          \
        gload_lds16(qa + aoff0 + (size_t)(jt) * 64, &lds[sb][0][t * 16]);      \
        gload_lds16(qa + aoff1 + (size_t)(jt) * 64, &lds[sb][0][t * 16 + 8192]); \
    }
#define STAGE_B(sb, jt)                                                        \
    {                                                                          \
        gload_lds16(wq + boff0 + (size_t)(jt) * 64, &lds[sb][1][t * 16]);      \
        gload_lds16(wq + boff1 + (size_t)(jt) * 64, &lds[sb][1][t * 16 + 8192]); \
    }

#define READ_AHI(s)                                                            \
    {                                                                          \
        _Pragma("unroll") for (int mf = 0; mf < 4; ++mf)                       \
            ahi[mf] = *(const i32x4*)&lds[s][0][(wm * 128 + (mf + 4) * 16 +    \
                                                lrow) * 64 + rslot];           \
    }
#define READ_NEXT(s, ALO, BN)                                                  \
    {                                                                          \
        _Pragma("unroll") for (int nf = 0; nf < 4; ++nf)                       \
            BN[nf] = *(const i32x4*)&lds[s][1][(wn * 64 + nf * 16 + lrow) * 64 + rslot]; \
        _Pragma("unroll") for (int mf = 0; mf < 4; ++mf)                       \
            ALO[mf] = *(const i32x4*)&lds[s][0][(wm * 128 + mf * 16 + lrow) * 64 + rslot]; \
    }
#define MMLO(ALO, BC)                                                          \
    {                                                                          \
        __builtin_amdgcn_s_setprio(1);                                         \
        _Pragma("unroll") for (int mf = 0; mf < 4; ++mf)                       \
            _Pragma("unroll") for (int nf = 0; nf < 4; ++nf)                   \
                acc[mf][nf] = __builtin_amdgcn_mfma_i32_16x16x64_i8(           \
                    ALO[mf], BC[nf], acc[mf][nf], 0, 0, 0);                    \
        __builtin_amdgcn_s_setprio(0);                                         \
    }
#define MMHI(BC)                                                               \
    {                                                                          \
        __builtin_amdgcn_s_setprio(1);                                         \
        _Pragma("unroll") for (int mf = 0; mf < 4; ++mf)                       \
            _Pragma("unroll") for (int nf = 0; nf < 4; ++nf)                   \
                acc[mf + 4][nf] = __builtin_amdgcn_mfma_i32_16x16x64_i8(       \
                    ahi[mf], BC[nf], acc[mf + 4][nf], 0, 0, 0);                \
        __builtin_amdgcn_s_setprio(0);                                         \
    }
#define SB0 __builtin_amdgcn_sched_barrier(0);
#define BAR __builtin_amdgcn_s_barrier();
#define WAIT_LGKM(n) asm volatile("s_waitcnt lgkmcnt(" #n ")" ::: "memory");
#define WAIT_VM(n) asm volatile("s_waitcnt vmcnt(" #n ")" ::: "memory");

    // phase 0 of tile J: ds_read a_hi(J) [consumed next phase] | stage A(J+2)
    //   | vmcnt(2): tile J+1 landed (A(J+2) still in flight) | barrier
    //   | lgkm(4): previous phase's 8 reads (a_lo(J), b(J)) done | 16 MFMA lo.
#define PH0(J, ALO, BC)                                                        \
    {                                                                          \
        READ_AHI((J) & 3);                                                     \
        STAGE_A(((J) + 2) & 3, (J) + 2);                                       \
        WAIT_VM(2);                                                            \
        SB0;                                                                   \
        BAR;                                                                   \
        WAIT_LGKM(4);                                                          \
        SB0;                                                                   \
        MMLO(ALO, BC);                                                         \
    }
    // phase 1 of tile J: ds_read a_lo(J+1), b(J+1) into NEXT set | stage B(J+2)
    //   | barrier | lgkm(8): a_hi(J) done | 16 MFMA hi.
#define PH1(J, BC, ALON, BN)                                                   \
    {                                                                          \
        READ_NEXT(((J) + 1) & 3, ALON, BN);                                    \
        STAGE_B(((J) + 2) & 3, (J) + 2);                                       \
        SB0;                                                                   \
        BAR;                                                                   \
        WAIT_LGKM(8);                                                          \
        SB0;                                                                   \
        MMHI(BC);                                                              \
    }

    i32x4 acc[8][4] = {};
    i32x4 alo0[4], b0[4], alo1[4], b1[4], ahi[4];

    // prologue: stage tiles 0,1; tile-0 landed; prime reads of tile 0 into set 0
    STAGE_A(0, 0);
    STAGE_B(0, 0);
    STAGE_A(1, 1);
    STAGE_B(1, 1);
    WAIT_VM(4);
    SB0;
    BAR;
    READ_NEXT(0, alo0, b0);

    // main loop: j = 0..61 (tiles 62,63 handled in tail; stages reach tile 63)
    for (int jp = 0; jp < 31; ++jp) {
        const int j = jp * 2;
        PH0(j, alo0, b0);
        PH1(j, b0, alo1, b1);
        PH0(j + 1, alo1, b1);
        PH1(j + 1, b1, alo0, b0);
    }

    // tail j=62 (set 0): no staging left; drain DMA for tile 63 before its reads
    {
        READ_AHI(62 & 3);
        WAIT_VM(0);  // A(63), B(63) landed
        SB0;
        BAR;
        WAIT_LGKM(4);
        SB0;
        MMLO(alo0, b0);

        READ_NEXT(63 & 3, alo1, b1);
        SB0;
        BAR;
        WAIT_LGKM(8);
        SB0;
        MMHI(b0);
    }
    // tail j=63 (set 1)
    {
        READ_AHI(63 & 3);
        WAIT_LGKM(4);
        SB0;
        MMLO(alo1, b1);
        WAIT_LGKM(0);
        SB0;
        MMHI(b1);
    }

    // epilogue: C/D layout col = lane&15, row = (lane>>4)*4 + j
    const int r0 = bm * 256 + wm * 128;
    const int c0 = bn * 256 + wn * 64;
    float asc[8][4];
#pragma unroll
    for (int m = 0; m < 8; ++m)
#pragma unroll
        for (int jj = 0; jj < 4; ++jj)
            asc[m][jj] = ascale[r0 + m * 16 + lk * 4 + jj];
#pragma unroll
    for (int n = 0; n < 4; ++n) {
        const int col = c0 + n * 16 + lrow;
        const float wsc = wscale[col];
        const float bb = bias[col];
#pragma unroll
        for (int m = 0; m < 8; ++m) {
#pragma unroll
            for (int jj = 0; jj < 4; ++jj) {
                const int row = r0 + m * 16 + lk * 4 + jj;
                out[(size_t)row * N_DIM + col] = (float)acc[m][n][jj] * asc[m][jj] * wsc + bb;
            }
        }
    }
}

extern "C" void kernel_launch(void* const* d_in, const int* in_sizes, int n_in,
                              void* d_out, int out_size, void* d_ws, size_t ws_size,
                              hipStream_t stream) {
    const float* x = (const float*)d_in[0];
    const int* w32 = (const int*)d_in[1];  // int8 weights arrive as int32
    const float* wscale = (const float*)d_in[2];
    const float* bias = (const float*)d_in[3];
    float* out = (float*)d_out;

    int8_t* qa = (int8_t*)d_ws;                                     // M*K int8
    float* ascale = (float*)((char*)d_ws + (size_t)M_DIM * K_DIM);  // M f32
    int8_t* wq = (int8_t*)((char*)d_ws + (size_t)M_DIM * K_DIM +
                           (size_t)M_DIM * sizeof(float));          // N*K int8

    quant_pack<<<M_DIM + 2048, 256, 0, stream>>>(x, w32, qa, ascale, wq);
    gemm_i8<<<1536, 512, 0, stream>>>(qa, wq, ascale, wscale, bias, out);
}